// Round 9
// baseline (657.341 us; speedup 1.0000x reference)
//
#include <hip/hip_runtime.h>
#include <stdint.h>

// SparseMoE gfx950, Round 14.
// R13 post-mortem: 583->554 (best). Router+W1T 108us (predicted ✓). Dispatch
// sum ~330us vs 554 total -> ~220us = harness 512MiB poison fills + ~7 launch
// gaps. Cheapest controllable waste: router_reduce(6)+assign_all(4)+2 gaps.
// R14: fold reduce+assign INTO the router GEMM launch via last-finisher
// counters (no spin, dispatch-order-free): 16 rg counters (32 col-blocks each)
// -> 32nd finisher reduces its 128 tokens; 16th rg-finisher runs assign body.
// Device-scope fences around the handoffs (Ps/topi cross XCD L2s).
// 8 -> 6 launches. Everything else frozen from R13.
typedef unsigned short ushort_t;
typedef __attribute__((ext_vector_type(8))) short short8;
typedef __attribute__((ext_vector_type(4))) float f32x4;

#define EMBED   1024
#define DFF     4096
#define NEXP    8
#define TOKENS  2048
#define SLOTS   4096
#define TMAX    40    // >= max Sum_e ceil(cnt_e/128) = 32+7 = 39
#define TG      ((TMAX + 7) / 8)   // t-groups per XCD

__device__ __forceinline__ ushort_t f2bf(float f) {
  unsigned u = __float_as_uint(f);
  u += 0x7FFFu + ((u >> 16) & 1u);   // RNE
  return (ushort_t)(u >> 16);
}
__device__ __forceinline__ float bf2f(ushort_t b) {
  return __uint_as_float(((unsigned)b) << 16);
}

// async 16B/lane global->LDS DMA. LDS dest wave-uniform; lane i lands at +16*i.
__device__ __forceinline__ void gl2lds16(const void* g, void* l) {
  typedef const __attribute__((address_space(1))) unsigned char* gp_t;
  typedef __attribute__((address_space(3))) unsigned char* lp_t;
  __builtin_amdgcn_global_load_lds((gp_t)(uintptr_t)g, (lp_t)(uintptr_t)l, 16, 0, 0);
}

// transpose+convert 64x64 tile: dst[n][dst_koff+k] = bf16(src[k][n]) (lo: residual)
__device__ __forceinline__ void transp_body(const float* __restrict__ src,
                                            ushort_t* __restrict__ dst,
                                            int src_ld, int dst_ld, int bx, int by,
                                            int dst_koff, int lo, float (*t)[65])
{
  int n0 = bx * 64, k0 = by * 64;
  int tid = threadIdx.x;
  int kk = tid >> 4, nn = (tid & 15) * 4;
  #pragma unroll
  for (int it = 0; it < 4; it++) {
    float4 v = *(const float4*)(src + (size_t)(k0 + kk + it * 16) * src_ld + n0 + nn);
    t[kk + it * 16][nn]     = v.x;
    t[kk + it * 16][nn + 1] = v.y;
    t[kk + it * 16][nn + 2] = v.z;
    t[kk + it * 16][nn + 3] = v.w;
  }
  __syncthreads();
  int nn2 = tid >> 3, kk2 = (tid & 7) * 8;
  #pragma unroll
  for (int it = 0; it < 2; it++) {
    int n = nn2 + it * 32;
    union { ushort_t u[8]; uint4 v; } pk;
    #pragma unroll
    for (int j = 0; j < 8; j++) {
      float xv = t[kk2 + j][n];
      ushort_t hv = f2bf(xv);
      pk.u[j] = lo ? f2bf(xv - bf2f(hv)) : hv;
    }
    *(uint4*)(dst + (size_t)(n0 + n) * dst_ld + dst_koff + k0 + kk2) = pk.v;
  }
}

// standalone transpose (fallback path only)
__global__ void transp_conv(const float* __restrict__ src, ushort_t* __restrict__ dst,
                            int src_ld, int dst_ld, long src_estride, long dst_estride,
                            int dst_koff, int lo)
{
  __shared__ __align__(16) float t[64][65];
  transp_body(src + (size_t)blockIdx.z * src_estride,
              dst + (size_t)blockIdx.z * dst_estride,
              src_ld, dst_ld, blockIdx.x, blockIdx.y, dst_koff, lo, t);
}

// prep: zero counts+rg/done counters + split x -> Xhl [xh|xl] + single-pass
// rw1 transpose (one 64x64 read writes RW1t segments {0:wh, 1024:wh, 2048:wl}).
__global__ __launch_bounds__(256) void prep_kernel(const float* __restrict__ x,
    ushort_t* __restrict__ Xs, const float* __restrict__ rw1,
    ushort_t* __restrict__ RW1t, int* __restrict__ counts)
{
  __shared__ __align__(16) float tt[64][65];
  int bid = blockIdx.x;
  if (bid < TOKENS) {
    if (bid == 0 && threadIdx.x < 64) counts[threadIdx.x] = 0;  // [0..7] cnt, [16..31] rg, [32] done
    int d = threadIdx.x * 4;
    float4 v = *(const float4*)(x + (size_t)bid * EMBED + d);
    ushort4 hi, lo;
    hi.x = f2bf(v.x); lo.x = f2bf(v.x - bf2f(hi.x));
    hi.y = f2bf(v.y); lo.y = f2bf(v.y - bf2f(hi.y));
    hi.z = f2bf(v.z); lo.z = f2bf(v.z - bf2f(hi.z));
    hi.w = f2bf(v.w); lo.w = f2bf(v.w - bf2f(hi.w));
    ushort_t* row = Xs + (size_t)bid * 2048;
    *(ushort4*)(row + d)        = hi;
    *(ushort4*)(row + 1024 + d) = lo;
    return;
  }
  int idx = bid - TOKENS;              // 1024 transp blocks, triple-write
  int n0 = (idx & 63) * 64, k0 = (idx >> 6) * 64;
  int tid = threadIdx.x;
  int kk = tid >> 4, nn = (tid & 15) * 4;
  #pragma unroll
  for (int it = 0; it < 4; it++) {
    float4 v = *(const float4*)(rw1 + (size_t)(k0 + kk + it * 16) * DFF + n0 + nn);
    tt[kk + it * 16][nn]     = v.x;
    tt[kk + it * 16][nn + 1] = v.y;
    tt[kk + it * 16][nn + 2] = v.z;
    tt[kk + it * 16][nn + 3] = v.w;
  }
  __syncthreads();
  int nn2 = tid >> 3, kk2 = (tid & 7) * 8;
  #pragma unroll
  for (int it = 0; it < 2; it++) {
    int n = nn2 + it * 32;
    union { ushort_t u[8]; uint4 v; } ph, pl;
    #pragma unroll
    for (int j = 0; j < 8; j++) {
      float xv = tt[kk2 + j][n];
      ushort_t hv = f2bf(xv);
      ph.u[j] = hv;
      pl.u[j] = f2bf(xv - bf2f(hv));
    }
    ushort_t* row = RW1t + (size_t)(n0 + n) * 3072 + k0 + kk2;
    *(uint4*)(row)        = ph.v;   // wh  (k' 0..1023)
    *(uint4*)(row + 1024) = ph.v;   // wh  (k' 1024..2047, pairs with xl)
    *(uint4*)(row + 2048) = pl.v;   // wl  (k' 2048..3071, pairs with xh)
  }
}

// ---------------- MFMA GEMM (depth-2 counted-vmcnt pipeline) ----------------
// 128x128 tile, BK=32, 4 waves 2x2, 4x4 mfma_16x16x32_bf16.  [R10-proven loop]
// Triple-buffered LDS (48KB), chunk-XOR swizzle slot(q,row)=q^((row>>1)&3).
// APATH 0: direct rows, stride K. 1: router Xhl, stride 2048 w/ k-fold.
//       2: gather rows via slot_token, stride 2048.
// EXPERT decode (XCD-chunked): xcd=bid&7; j=bid>>3; t=xcd+8*(j/INNER).
// OUTMODE 0: f32. 1: bf16. 3: f32 gated partial [kc][slot][c].
//         4: fused router-score partials (slot_gate = rw2 [DFF][8]) + in-launch
//            last-finisher reduce (per 16 row-groups) + assign (last rg).
// TSHAPE>0: blocks >= ngb run weight-transpose tiles and exit
//   (1 = W1 [1024][4096] geometry, 2 = W2 [4096][1024]).
template<int APATH, int OUTMODE, bool RELU, bool EXPERT, int SPLITK, int NX, int TSHAPE>
__global__ __launch_bounds__(256, 3)
void gemm_kernel(const ushort_t* __restrict__ A, const ushort_t* __restrict__ B,
                 const float* __restrict__ bias, void* __restrict__ Cout,
                 const float* __restrict__ slot_gate, const int* __restrict__ slot_token,
                 const int* __restrict__ off, const int* __restrict__ tile_e,
                 const int* __restrict__ tile_y, int e0, int e1,
                 int M, int N, int K, int ngb,
                 const float* __restrict__ tsrc, ushort_t* __restrict__ tdst,
                 const float* __restrict__ r_rb2, int* r_topi, float* r_gates,
                 int* r_tok_slot, int* r_slot_token, float* r_slot_gate,
                 int* r_counts, int* r_off, int* r_tile_e, int* r_tile_y)
{
  __shared__ __align__(16) char lds_raw[49152];
  __shared__ int s_role;
  auto As = (ushort_t(*)[4096])lds_raw;
  auto Bs = (ushort_t(*)[4096])(lds_raw + 24576);

  if constexpr (TSHAPE > 0) {
    int bidf = blockIdx.x;
    if (bidf >= ngb) {               // weight-transpose tiles (horizontal fusion)
      int idx = bidf - ngb;
      auto tt = (float(*)[65])lds_raw;
      const size_t ES = (size_t)EMBED * DFF;
      if constexpr (TSHAPE == 1) {   // W1 [k=1024][n=4096] -> W1T [n][k]
        int bx = idx & 63, by = (idx >> 6) & 15, z = idx >> 10;
        transp_body(tsrc + z * ES, tdst + z * ES, DFF, EMBED, bx, by, 0, 0, tt);
      } else {                       // W2 [k=4096][n=1024] -> W2T [n][k]
        int bx = idx & 15, by = (idx >> 4) & 63, z = idx >> 10;
        transp_body(tsrc + z * ES, tdst + z * ES, EMBED, DFF, bx, by, 0, 0, tt);
      }
      return;
    }
  }

  int e = 0, kc = 0, row0, col0, m_base, m_cnt;
  if (EXPERT) {
    constexpr int INNER = NX * SPLITK;
    int bid = blockIdx.x;
    int xcd = bid & 7;
    int j   = bid >> 3;
    int t   = xcd + 8 * (j / INNER);      // bijective over [0, 8*TG)
    int i   = j % INNER;
    int xi  = i % NX;
    kc      = i / NX;
    e = tile_e[t];
    if (e < e0 || e >= e1) return;        // padded tail / other range, uniform exit
    row0   = tile_y[t] * 128;
    col0   = xi * 128;
    m_base = off[e];
    m_cnt  = off[e + 1] - m_base;
  } else {
    int bid = blockIdx.x;                 // 1-D: 32 col-tiles x (M/128) row-tiles
    row0 = (bid >> 5) * 128;
    col0 = (bid & 31) * 128;
    m_base = 0; m_cnt = M;
    if (row0 >= m_cnt) return;
  }
  const int Kc   = K / SPLITK;
  const int kbeg = kc * Kc;

  const int tid  = threadIdx.x;
  const int lane = tid & 63;
  const int wid  = tid >> 6;
  const int wm = wid & 1, wn = wid >> 1;

  // staging lane constants (DMA): lane i -> tile row base+(i>>2), slot i&3,
  // fetched global chunk = (i&3) ^ ((i>>3)&3)
  const int srow  = lane >> 2;
  const int schk8 = ((lane & 3) ^ ((lane >> 3) & 3)) * 8;

  const ushort_t* gA[2];
  const ushort_t* gB[2];
  int aoff[2];
  const ushort_t* Bt = B + (EXPERT ? (size_t)(e - e0) * (size_t)N * K : 0);
  #pragma unroll
  for (int h = 0; h < 2; h++) {
    int r  = row0 + h * 64 + wid * 16 + srow;
    int rl = min(r, m_cnt - 1);              // clamp; OOB rows discarded in epilogue
    size_t rowb;
    if (APATH == 2)      rowb = (size_t)slot_token[m_base + rl] * 2048;
    else if (APATH == 1) rowb = (size_t)rl * 2048;
    else                 rowb = (size_t)(m_base + rl) * (size_t)K;
    gA[h]   = A + rowb + (APATH == 0 ? kbeg : 0) + schk8;
    aoff[h] = (h * 64 + wid * 16) * 32;

    int n = col0 + h * 64 + wid * 16 + srow;
    gB[h] = Bt + (size_t)n * K + kbeg + schk8;
  }

  // per wave: 4 DMAs per stage (2 A + 2 B) -> counted vmcnt(4)
  auto stage = [&](int pb, int kt) {
    const int k0 = kt << 5;
    // router fold: k' in [2048,3072) reads xh cols k'-2048 (boundary 32-aligned,
    // k0 wave-uniform -> uniform select, never straddles within a chunk)
    const int k0a = (APATH == 1 && k0 >= 2048) ? k0 - 2048 : k0;
    #pragma unroll
    for (int h = 0; h < 2; h++) {
      gl2lds16(gA[h] + k0a, &As[pb][aoff[h]]);
      gl2lds16(gB[h] + k0,  &Bs[pb][aoff[h]]);
    }
  };

  f32x4 acc[4][4];
  #pragma unroll
  for (int i = 0; i < 4; i++)
    #pragma unroll
    for (int j = 0; j < 4; j++)
      acc[i][j] = (f32x4){0.f, 0.f, 0.f, 0.f};

  // fragment read constants
  const int q  = lane >> 4;
  const int rr = lane & 15;
  const int sw8 = (q ^ ((rr >> 1) & 3)) * 8;
  const int abase = (wm * 64 + rr) * 32 + sw8;
  const int bbase = (wn * 64 + rr) * 32 + sw8;

  const int nkt = Kc >> 5;

  stage(0, 0);
  if (nkt > 1) stage(1, 1);

  for (int kt = 0; kt < nkt; kt++) {
    // tile kt complete when <=4 outstanding (only stage(kt+1) newer).
    if (kt + 1 < nkt) asm volatile("s_waitcnt vmcnt(4)" ::: "memory");
    else              asm volatile("s_waitcnt vmcnt(0)" ::: "memory");
    __builtin_amdgcn_s_barrier();          // all waves' tile-kt DMAs landed
    __builtin_amdgcn_sched_barrier(0);
    // buf[(kt+2)%3] was read at kt-1; every wave passed its kt-1 lgkmcnt(0)
    // before this barrier -> safe to overwrite now.
    if (kt + 2 < nkt) stage((kt + 2) % 3, kt + 2);

    const int cur = kt % 3;
    short8 af[4], bfr[4];
    #pragma unroll
    for (int i = 0; i < 4; i++) {
      af[i]  = *(const short8*)(&As[cur][abase + i * 512]);
      bfr[i] = *(const short8*)(&Bs[cur][bbase + i * 512]);
    }
    asm volatile("s_waitcnt lgkmcnt(0)" ::: "memory");
    __builtin_amdgcn_sched_barrier(0);     // rule 18: keep MFMAs below the wait
    #pragma unroll
    for (int mt = 0; mt < 4; mt++)
      #pragma unroll
      for (int nt = 0; nt < 4; nt++)
        acc[mt][nt] = __builtin_amdgcn_mfma_f32_16x16x32_bf16(af[mt], bfr[nt], acc[mt][nt], 0, 0, 0);
  }

  // epilogue. C/D layout: col=lane&15, row=(lane>>4)*4+i  (m89-verified)
  const float* biasp = bias + (EXPERT ? (size_t)e * N : 0);
  float bv[4];
  #pragma unroll
  for (int nt = 0; nt < 4; nt++)
    bv[nt] = biasp[col0 + wn * 64 + nt * 16 + rr];
  const float bscale = (SPLITK == 1 || kc == 0) ? 1.f : 0.f;

  if constexpr (OUTMODE == 4) {
    // fused router score: partial[row][xi2][e] = sum_{c in 64-col chunk}
    // relu(h[row][c]) * rw2[c][e].  xi2 = (col0>>6)+wn.
    const float* rw2p = slot_gate;           // repurposed: rw2 [DFF][8]
    float4 wa[4], wb[4];
    #pragma unroll
    for (int nt = 0; nt < 4; nt++) {
      int c = col0 + wn * 64 + nt * 16 + rr;
      wa[nt] = *(const float4*)(rw2p + (size_t)c * 8);
      wb[nt] = *(const float4*)(rw2p + (size_t)c * 8 + 4);
    }
    float* Ps = (float*)Cout;
    const int xi2 = (col0 >> 6) + wn;
    #pragma unroll
    for (int mt = 0; mt < 4; mt++) {
      #pragma unroll
      for (int i = 0; i < 4; i++) {
        float4 sA = {0.f, 0.f, 0.f, 0.f}, sB = {0.f, 0.f, 0.f, 0.f};
        #pragma unroll
        for (int nt = 0; nt < 4; nt++) {
          float v = acc[mt][nt][i] + bv[nt];
          if (RELU) v = fmaxf(v, 0.f);
          sA.x += v * wa[nt].x; sA.y += v * wa[nt].y;
          sA.z += v * wa[nt].z; sA.w += v * wa[nt].w;
          sB.x += v * wb[nt].x; sB.y += v * wb[nt].y;
          sB.z += v * wb[nt].z; sB.w += v * wb[nt].w;
        }
        #pragma unroll
        for (int o = 1; o <= 8; o <<= 1) {   // reduce over rr (16-lane group)
          sA.x += __shfl_xor(sA.x, o); sA.y += __shfl_xor(sA.y, o);
          sA.z += __shfl_xor(sA.z, o); sA.w += __shfl_xor(sA.w, o);
          sB.x += __shfl_xor(sB.x, o); sB.y += __shfl_xor(sB.y, o);
          sB.z += __shfl_xor(sB.z, o); sB.w += __shfl_xor(sB.w, o);
        }
        if (rr == 0) {
          int row = row0 + wm * 64 + mt * 16 + q * 4 + i;
          float* p = Ps + ((size_t)row * 64 + xi2) * 8;
          *(float4*)p       = sA;
          *(float4*)(p + 4) = sB;
        }
      }
    }

    // ---- in-launch fused reduce (last col-block per row-group) + assign ----
    __threadfence();                       // release this thread's Ps stores
    __syncthreads();
    const int rg = (int)(blockIdx.x >> 5); // 16 row-groups x 32 col-blocks
    if (tid == 0)
      s_role = (atomicAdd(&r_counts[16 + rg], 1) == 31);
    __syncthreads();
    if (s_role) {
      __threadfence();                     // acquire remote Ps for this rg
      for (int it = 0; it < 32; it++) {    // 128 tokens, 4 waves
        int t = rg * 128 + it * 4 + (tid >> 6);
        const float* pt = Ps + (size_t)t * 512;
        float4 v0 = *(const float4*)(pt + lane * 8);
        float4 v1 = *(const float4*)(pt + lane * 8 + 4);
        #pragma unroll
        for (int o = 1; o <= 32; o <<= 1) {
          v0.x += __shfl_xor(v0.x, o); v0.y += __shfl_xor(v0.y, o);
          v0.z += __shfl_xor(v0.z, o); v0.w += __shfl_xor(v0.w, o);
          v1.x += __shfl_xor(v1.x, o); v1.y += __shfl_xor(v1.y, o);
          v1.z += __shfl_xor(v1.z, o); v1.w += __shfl_xor(v1.w, o);
        }
        if (lane == 0) {
          float s[8] = {v0.x + r_rb2[0], v0.y + r_rb2[1], v0.z + r_rb2[2], v0.w + r_rb2[3],
                        v1.x + r_rb2[4], v1.y + r_rb2[5], v1.z + r_rb2[6], v1.w + r_rb2[7]};
          int i0 = 0;
          #pragma unroll
          for (int ee = 1; ee < 8; ee++) if (s[ee] > s[i0]) i0 = ee;  // ties -> lower idx
          int i1 = (i0 == 0) ? 1 : 0;
          #pragma unroll
          for (int ee = 0; ee < 8; ee++) if (ee != i0 && s[ee] > s[i1]) i1 = ee;
          float ex = __expf(s[i1] - s[i0]);
          r_topi[t * 2] = i0; r_topi[t * 2 + 1] = i1;
          r_gates[t * 2] = 1.f / (1.f + ex); r_gates[t * 2 + 1] = ex / (1.f + ex);
          atomicAdd(&r_counts[i0], 1);
          atomicAdd(&r_counts[i1], 1);
        }
      }
      __threadfence();                     // release topi/gates
      __syncthreads();
      if (tid == 0)
        s_role = (atomicAdd(&r_counts[32], 1) == 15);
      __syncthreads();
      if (s_role) {                        // last row-group: assign body
        __threadfence();                   // acquire all topi/gates/counts
        int* s_off = (int*)lds_raw;
        int* s_cur = (int*)lds_raw + 8;
        if (tid < NEXP) s_cur[tid] = 0;
        if (tid == 0) {
          int a = 0, t = 0;
          for (int ee = 0; ee < NEXP; ee++) {
            r_off[ee] = a; s_off[ee] = a;
            int c = r_counts[ee]; a += c;
            int ty = (c + 127) >> 7;
            for (int y = 0; y < ty; y++) { r_tile_e[t] = ee; r_tile_y[t] = y; t++; }
          }
          r_off[NEXP] = a;
          for (; t < TMAX; t++) { r_tile_e[t] = -1; r_tile_y[t] = 0; }
        }
        __syncthreads();
        for (int t = tid; t < TOKENS; t += 256) {
          #pragma unroll
          for (int k = 0; k < 2; k++) {
            int ee = r_topi[t * 2 + k];
            int pp = atomicAdd(&s_cur[ee], 1);
            int s = s_off[ee] + pp;
            r_slot_token[s] = t;
            r_slot_gate[s]  = r_gates[t * 2 + k];
            r_tok_slot[t * 2 + k] = s;
          }
        }
      }
    }
  } else {
    #pragma unroll
    for (int mt = 0; mt < 4; mt++) {
      #pragma unroll
      for (int i = 0; i < 4; i++) {
        int r_loc = row0 + wm * 64 + mt * 16 + q * 4 + i;
        if (r_loc < m_cnt) {
          int slot = m_base + r_loc;
          float g = 1.f;
          if (OUTMODE == 3) g = slot_gate[slot];
          #pragma unroll
          for (int nt = 0; nt < 4; nt++) {
            float v = acc[mt][nt][i] + bscale * bv[nt];
            if (RELU) v = fmaxf(v, 0.f);
            int c = col0 + wn * 64 + nt * 16 + rr;
            if (OUTMODE == 0)      ((float*)Cout)[(size_t)slot * N + c]    = v;
            else if (OUTMODE == 1) ((ushort_t*)Cout)[(size_t)slot * N + c] = f2bf(v);
            else ((float*)Cout)[((size_t)kc * SLOTS + slot) * N + c] = g * v;
          }
        }
      }
    }
  }
}

// out[t] = sum over {2 slots} x {NC k-chunks} of gated partials (gate/bias folded)
template<int NC>
__global__ void combine_out(const float* __restrict__ Ys, const int* __restrict__ tok_slot,
                            float* __restrict__ out)
{
  int t = blockIdx.x;
  int d = threadIdx.x * 4;
  int s0 = tok_slot[t * 2], s1 = tok_slot[t * 2 + 1];
  float4 o = {0.f, 0.f, 0.f, 0.f};
  #pragma unroll
  for (int k = 0; k < NC; k++) {
    float4 a = *(const float4*)(Ys + ((size_t)k * SLOTS + s0) * EMBED + d);
    float4 b = *(const float4*)(Ys + ((size_t)k * SLOTS + s1) * EMBED + d);
    o.x += a.x + b.x;
    o.y += a.y + b.y;
    o.z += a.z + b.z;
    o.w += a.w + b.w;
  }
  *(float4*)(out + (size_t)t * EMBED + d) = o;
}

extern "C" void kernel_launch(void* const* d_in, const int* in_sizes, int n_in,
                              void* d_out, int out_size, void* d_ws, size_t ws_size,
                              hipStream_t stream)
{
  const float* x   = (const float*)d_in[0];
  const float* rw1 = (const float*)d_in[1];
  const float* rb1 = (const float*)d_in[2];
  const float* rw2 = (const float*)d_in[3];
  const float* rb2 = (const float*)d_in[4];
  const float* W1  = (const float*)d_in[5];
  const float* b1  = (const float*)d_in[6];
  const float* W2  = (const float*)d_in[7];
  const float* b2  = (const float*)d_in[8];
  float* out = (float*)d_out;
  char* ws = (char*)d_ws;

  const long W1ES = (long)EMBED * DFF;   // floats per expert
  const long W2ES = (long)DFF * EMBED;
  const size_t SZ_R = (size_t)4096 * 4096 * 2;   // 33.5 MB

  const bool FULL = ws_size >= ((size_t)300 << 20);

  if (FULL) {
    // Full layout (~240 MB; ws = 512 MiB per R8 fill evidence):
    // [W1T 67][W2T 67][RW1t 25.2][Hs 33.5][Xhl 8.4][Ys(2) 33.5][Ps 4][small]
    char* p = ws;
    ushort_t* W1T  = (ushort_t*)p;  p += (size_t)NEXP * DFF * EMBED * 2;
    ushort_t* W2T  = (ushort_t*)p;  p += (size_t)NEXP * EMBED * DFF * 2;
    ushort_t* RW1t = (ushort_t*)p;  p += (size_t)4096 * 3072 * 2;
    ushort_t* Hs   = (ushort_t*)p;  p += (size_t)SLOTS * DFF * 2;
    ushort_t* Xhl  = (ushort_t*)p;  p += (size_t)TOKENS * 2048 * 2;
    float*    Ys   = (float*)p;     p += (size_t)2 * SLOTS * EMBED * 4;
    float*    Ps   = (float*)p;     p += (size_t)TOKENS * 512 * 4;
    int*   topi       = (int*)p;    p += TOKENS * 2 * 4;
    float* gates      = (float*)p;  p += TOKENS * 2 * 4;
    int*   tok_slot   = (int*)p;    p += TOKENS * 2 * 4;
    int*   slot_token = (int*)p;    p += SLOTS * 4;
    float* slot_gate  = (float*)p;  p += SLOTS * 4;
    int*   counts     = (int*)p;    p += 256;  // [0..7] cnt, [16..31] rg, [32] done
    int*   off        = (int*)p;    p += 256;
    int*   tile_e     = (int*)p;    p += 256;
    int*   tile_y     = (int*)p;    p += 256;

    // (1) prep: zero counters + split + single-pass rw1 transpose
    prep_kernel<<<TOKENS + 1024, 256, 0, stream>>>(x, Xhl, rw1, RW1t, counts);

    // (2) Router GEMM (512 blocks @3/CU) + W1T transp + in-launch reduce+assign
    gemm_kernel<1, 4, true, false, 1, 32, 1>
        <<<dim3(512 + 8192, 1, 1), 256, 0, stream>>>(Xhl, RW1t, rb1, Ps, rw2,
            nullptr, nullptr, nullptr, nullptr, 0, NEXP, TOKENS, DFF, 3072,
            512, W1, W1T,
            rb2, topi, gates, tok_slot, slot_token, slot_gate, counts,
            off, tile_e, tile_y);

    // (3) GEMM1 (reads W1T + assign outputs) + W2T transp
    gemm_kernel<2, 1, true, true, 1, 32, 2>
        <<<dim3(8 * TG * 32 + 8192, 1, 1), 256, 0, stream>>>(Xhl, W1T, b1, Hs,
            nullptr, slot_token, off, tile_e, tile_y, 0, NEXP, 0, DFF, EMBED,
            8 * TG * 32, W2, W2T,
            nullptr, nullptr, nullptr, nullptr, nullptr, nullptr, nullptr,
            nullptr, nullptr, nullptr);

    // (4) GEMM2 SPLITK=2 (640 blocks fit 768 slots)
    gemm_kernel<0, 3, false, true, 2, 8, 0>
        <<<dim3(8 * TG * 16, 1, 1), 256, 0, stream>>>(Hs, W2T, b2, Ys,
            slot_gate, nullptr, off, tile_e, tile_y, 0, NEXP, 0, EMBED, DFF,
            0, nullptr, nullptr,
            nullptr, nullptr, nullptr, nullptr, nullptr, nullptr, nullptr,
            nullptr, nullptr, nullptr);

    combine_out<2><<<TOKENS, 256, 0, stream>>>(Ys, tok_slot, out);
  } else {
    // Fallback: half-by-half weight staging (~109 MB proven)
    ushort_t* RW1t = (ushort_t*)ws;                 // region A
    ushort_t* WT   = (ushort_t*)ws;
    ushort_t* Hs   = (ushort_t*)(ws + SZ_R);        // region B
    ushort_t* Xhl  = (ushort_t*)(ws + 2 * SZ_R);    // region C
    float*    Ys   = (float*)(ws + 2 * SZ_R);
    char* p = ws + 3 * SZ_R;
    float* Ps         = (float*)p;  p += (size_t)TOKENS * 512 * 4;  // 4MB
    int*   topi       = (int*)p;    p += TOKENS * 2 * 4;
    float* gates      = (float*)p;  p += TOKENS * 2 * 4;
    int*   tok_slot   = (int*)p;    p += TOKENS * 2 * 4;
    int*   slot_token = (int*)p;    p += SLOTS * 4;
    float* slot_gate  = (float*)p;  p += SLOTS * 4;
    int*   counts     = (int*)p;    p += 256;
    int*   off        = (int*)p;    p += 256;
    int*   tile_e     = (int*)p;    p += 256;
    int*   tile_y     = (int*)p;    p += 256;

    prep_kernel<<<TOKENS + 1024, 256, 0, stream>>>(x, Xhl, rw1, RW1t, counts);

    gemm_kernel<1, 4, true, false, 1, 32, 0>
        <<<dim3(512, 1, 1), 256, 0, stream>>>(Xhl, RW1t, rb1, Ps, rw2, nullptr,
            nullptr, nullptr, nullptr, 0, NEXP, TOKENS, DFF, 3072,
            0, nullptr, nullptr,
            rb2, topi, gates, tok_slot, slot_token, slot_gate, counts,
            off, tile_e, tile_y);

    for (int half = 0; half < 2; half++) {
      int e0 = half * 4;
      transp_conv<<<dim3(64, 16, 4), 256, 0, stream>>>(W1 + (size_t)e0 * W1ES, WT,
          DFF, EMBED, W1ES, W1ES, 0, 0);
      gemm_kernel<2, 1, true, true, 1, 32, 0>
          <<<dim3(8 * TG * 32, 1, 1), 256, 0, stream>>>(Xhl, WT, b1, Hs,
              nullptr, slot_token, off, tile_e, tile_y, e0, e0 + 4, 0, DFF, EMBED,
              0, nullptr, nullptr,
              nullptr, nullptr, nullptr, nullptr, nullptr, nullptr, nullptr,
              nullptr, nullptr, nullptr);
    }
    for (int half = 0; half < 2; half++) {
      int e0 = half * 4;
      transp_conv<<<dim3(16, 64, 4), 256, 0, stream>>>(W2 + (size_t)e0 * W2ES, WT,
          EMBED, DFF, W2ES, W2ES, 0, 0);
      gemm_kernel<0, 3, false, true, 2, 8, 0>
          <<<dim3(8 * TG * 16, 1, 1), 256, 0, stream>>>(Hs, WT, b2, Ys,
              slot_gate, nullptr, off, tile_e, tile_y, e0, e0 + 4, 0, EMBED, DFF,
              0, nullptr, nullptr,
              nullptr, nullptr, nullptr, nullptr, nullptr, nullptr, nullptr,
              nullptr, nullptr, nullptr);
    }

    combine_out<2><<<TOKENS, 256, 0, stream>>>(Ys, tok_slot, out);
  }
}

// Round 10
// 551.052 us; speedup vs baseline: 1.1929x; 1.1929x over previous
//
#include <hip/hip_runtime.h>
#include <stdint.h>

// SparseMoE gfx950, Round 15.
// R14 post-mortem: SEVERE regression (554->657). In-launch last-finisher
// reduce+assign required device-scope __threadfence(); on gfx950 that is an
// L2 writeback/invalidate (per-XCD L2s are non-coherent). 512 fences inside a
// launch with 8192 L2-dependent streamer blocks destroyed all locality
// (router launch 108->278us, HBM 24->9.5%). RULE: cross-block handoffs cost
// an L2 flush on CDNA4 -- only in tiny dedicated kernels, never inside
// bandwidth-consuming launches.
// R15: revert to R13 (proven 553.9) + one zero-risk cut: router B-side fold.
// RW1t's k'[1024,2048) segment was a byte-copy of [0,1024) (both wh); fold it
// in addressing (B stride 2048, k0>=1024 -> k0-1024). RW1t 25.2->16.8MB,
// prep writes one less segment, smaller router B footprint.
typedef unsigned short ushort_t;
typedef __attribute__((ext_vector_type(8))) short short8;
typedef __attribute__((ext_vector_type(4))) float f32x4;

#define EMBED   1024
#define DFF     4096
#define NEXP    8
#define TOKENS  2048
#define SLOTS   4096
#define TMAX    40    // >= max Sum_e ceil(cnt_e/128) = 32+7 = 39
#define TG      ((TMAX + 7) / 8)   // t-groups per XCD

__device__ __forceinline__ ushort_t f2bf(float f) {
  unsigned u = __float_as_uint(f);
  u += 0x7FFFu + ((u >> 16) & 1u);   // RNE
  return (ushort_t)(u >> 16);
}
__device__ __forceinline__ float bf2f(ushort_t b) {
  return __uint_as_float(((unsigned)b) << 16);
}

// async 16B/lane global->LDS DMA. LDS dest wave-uniform; lane i lands at +16*i.
__device__ __forceinline__ void gl2lds16(const void* g, void* l) {
  typedef const __attribute__((address_space(1))) unsigned char* gp_t;
  typedef __attribute__((address_space(3))) unsigned char* lp_t;
  __builtin_amdgcn_global_load_lds((gp_t)(uintptr_t)g, (lp_t)(uintptr_t)l, 16, 0, 0);
}

// transpose+convert 64x64 tile: dst[n][dst_koff+k] = bf16(src[k][n]) (lo: residual)
__device__ __forceinline__ void transp_body(const float* __restrict__ src,
                                            ushort_t* __restrict__ dst,
                                            int src_ld, int dst_ld, int bx, int by,
                                            int dst_koff, int lo, float (*t)[65])
{
  int n0 = bx * 64, k0 = by * 64;
  int tid = threadIdx.x;
  int kk = tid >> 4, nn = (tid & 15) * 4;
  #pragma unroll
  for (int it = 0; it < 4; it++) {
    float4 v = *(const float4*)(src + (size_t)(k0 + kk + it * 16) * src_ld + n0 + nn);
    t[kk + it * 16][nn]     = v.x;
    t[kk + it * 16][nn + 1] = v.y;
    t[kk + it * 16][nn + 2] = v.z;
    t[kk + it * 16][nn + 3] = v.w;
  }
  __syncthreads();
  int nn2 = tid >> 3, kk2 = (tid & 7) * 8;
  #pragma unroll
  for (int it = 0; it < 2; it++) {
    int n = nn2 + it * 32;
    union { ushort_t u[8]; uint4 v; } pk;
    #pragma unroll
    for (int j = 0; j < 8; j++) {
      float xv = t[kk2 + j][n];
      ushort_t hv = f2bf(xv);
      pk.u[j] = lo ? f2bf(xv - bf2f(hv)) : hv;
    }
    *(uint4*)(dst + (size_t)(n0 + n) * dst_ld + dst_koff + k0 + kk2) = pk.v;
  }
}

// standalone transpose (fallback path only)
__global__ void transp_conv(const float* __restrict__ src, ushort_t* __restrict__ dst,
                            int src_ld, int dst_ld, long src_estride, long dst_estride,
                            int dst_koff, int lo)
{
  __shared__ __align__(16) float t[64][65];
  transp_body(src + (size_t)blockIdx.z * src_estride,
              dst + (size_t)blockIdx.z * dst_estride,
              src_ld, dst_ld, blockIdx.x, blockIdx.y, dst_koff, lo, t);
}

// prep: zero counts + split x -> Xhl [xh|xl] + single-pass rw1 transpose:
// one 64x64 read of rw1 writes RW1t [n][2048] segments {0:wh, 1024:wl}.
__global__ __launch_bounds__(256) void prep_kernel(const float* __restrict__ x,
    ushort_t* __restrict__ Xs, const float* __restrict__ rw1,
    ushort_t* __restrict__ RW1t, int* __restrict__ counts)
{
  __shared__ __align__(16) float tt[64][65];
  int bid = blockIdx.x;
  if (bid < TOKENS) {
    if (bid == 0 && threadIdx.x < NEXP) counts[threadIdx.x] = 0;
    int d = threadIdx.x * 4;
    float4 v = *(const float4*)(x + (size_t)bid * EMBED + d);
    ushort4 hi, lo;
    hi.x = f2bf(v.x); lo.x = f2bf(v.x - bf2f(hi.x));
    hi.y = f2bf(v.y); lo.y = f2bf(v.y - bf2f(hi.y));
    hi.z = f2bf(v.z); lo.z = f2bf(v.z - bf2f(hi.z));
    hi.w = f2bf(v.w); lo.w = f2bf(v.w - bf2f(hi.w));
    ushort_t* row = Xs + (size_t)bid * 2048;
    *(ushort4*)(row + d)        = hi;
    *(ushort4*)(row + 1024 + d) = lo;
    return;
  }
  int idx = bid - TOKENS;              // 1024 transp blocks, double-write
  int n0 = (idx & 63) * 64, k0 = (idx >> 6) * 64;
  int tid = threadIdx.x;
  int kk = tid >> 4, nn = (tid & 15) * 4;
  #pragma unroll
  for (int it = 0; it < 4; it++) {
    float4 v = *(const float4*)(rw1 + (size_t)(k0 + kk + it * 16) * DFF + n0 + nn);
    tt[kk + it * 16][nn]     = v.x;
    tt[kk + it * 16][nn + 1] = v.y;
    tt[kk + it * 16][nn + 2] = v.z;
    tt[kk + it * 16][nn + 3] = v.w;
  }
  __syncthreads();
  int nn2 = tid >> 3, kk2 = (tid & 7) * 8;
  #pragma unroll
  for (int it = 0; it < 2; it++) {
    int n = nn2 + it * 32;
    union { ushort_t u[8]; uint4 v; } ph, pl;
    #pragma unroll
    for (int j = 0; j < 8; j++) {
      float xv = tt[kk2 + j][n];
      ushort_t hv = f2bf(xv);
      ph.u[j] = hv;
      pl.u[j] = f2bf(xv - bf2f(hv));
    }
    ushort_t* row = RW1t + (size_t)(n0 + n) * 2048 + k0 + kk2;
    *(uint4*)(row)        = ph.v;   // wh  (B k' 0..1023; also serves 1024..2047)
    *(uint4*)(row + 1024) = pl.v;   // wl  (B k' 2048..3071 via fold)
  }
}

// ---------------- MFMA GEMM (depth-2 counted-vmcnt pipeline) ----------------
// 128x128 tile, BK=32, 4 waves 2x2, 4x4 mfma_16x16x32_bf16.  [R10-proven loop]
// Triple-buffered LDS (48KB), chunk-XOR swizzle slot(q,row)=q^((row>>1)&3).
// APATH 0: direct rows, stride K. 1: router Xhl, stride 2048 w/ A k-fold
//   (k'>=2048 -> xh cols k'-2048) and B k-fold (k'>=1024 -> k'-1024, B stride
//   2048: wh serves k'[0,2048), wl at [1024,2048) serves k'[2048,3072)).
//       2: gather rows via slot_token, stride 2048.
// EXPERT decode (XCD-chunked): xcd=bid&7; j=bid>>3; t=xcd+8*(j/INNER).
// OUTMODE 0: f32. 1: bf16. 3: f32 gated partial [kc][slot][c].
//         4: fused router-score partials (slot_gate = rw2 [DFF][8]).
// TSHAPE>0: blocks >= ngb run weight-transpose tiles and exit
//   (1 = W1 [1024][4096] geometry, 2 = W2 [4096][1024]).
template<int APATH, int OUTMODE, bool RELU, bool EXPERT, int SPLITK, int NX, int TSHAPE>
__global__ __launch_bounds__(256, 3)
void gemm_kernel(const ushort_t* __restrict__ A, const ushort_t* __restrict__ B,
                 const float* __restrict__ bias, void* __restrict__ Cout,
                 const float* __restrict__ slot_gate, const int* __restrict__ slot_token,
                 const int* __restrict__ off, const int* __restrict__ tile_e,
                 const int* __restrict__ tile_y, int e0, int e1,
                 int M, int N, int K, int ngb,
                 const float* __restrict__ tsrc, ushort_t* __restrict__ tdst)
{
  __shared__ __align__(16) char lds_raw[49152];
  auto As = (ushort_t(*)[4096])lds_raw;
  auto Bs = (ushort_t(*)[4096])(lds_raw + 24576);

  if constexpr (TSHAPE > 0) {
    int bidf = blockIdx.x;
    if (bidf >= ngb) {               // weight-transpose tiles (horizontal fusion)
      int idx = bidf - ngb;
      auto tt = (float(*)[65])lds_raw;
      const size_t ES = (size_t)EMBED * DFF;
      if constexpr (TSHAPE == 1) {   // W1 [k=1024][n=4096] -> W1T [n][k]
        int bx = idx & 63, by = (idx >> 6) & 15, z = idx >> 10;
        transp_body(tsrc + z * ES, tdst + z * ES, DFF, EMBED, bx, by, 0, 0, tt);
      } else {                       // W2 [k=4096][n=1024] -> W2T [n][k]
        int bx = idx & 15, by = (idx >> 4) & 63, z = idx >> 10;
        transp_body(tsrc + z * ES, tdst + z * ES, EMBED, DFF, bx, by, 0, 0, tt);
      }
      return;
    }
  }

  int e = 0, kc = 0, row0, col0, m_base, m_cnt;
  if (EXPERT) {
    constexpr int INNER = NX * SPLITK;
    int bid = blockIdx.x;
    int xcd = bid & 7;
    int j   = bid >> 3;
    int t   = xcd + 8 * (j / INNER);      // bijective over [0, 8*TG)
    int i   = j % INNER;
    int xi  = i % NX;
    kc      = i / NX;
    e = tile_e[t];
    if (e < e0 || e >= e1) return;        // padded tail / other range, uniform exit
    row0   = tile_y[t] * 128;
    col0   = xi * 128;
    m_base = off[e];
    m_cnt  = off[e + 1] - m_base;
  } else {
    int bid = blockIdx.x;                 // 1-D: 32 col-tiles x (M/128) row-tiles
    row0 = (bid >> 5) * 128;
    col0 = (bid & 31) * 128;
    m_base = 0; m_cnt = M;
    if (row0 >= m_cnt) return;
  }
  const int Kc   = K / SPLITK;
  const int kbeg = kc * Kc;

  const int tid  = threadIdx.x;
  const int lane = tid & 63;
  const int wid  = tid >> 6;
  const int wm = wid & 1, wn = wid >> 1;

  // staging lane constants (DMA): lane i -> tile row base+(i>>2), slot i&3,
  // fetched global chunk = (i&3) ^ ((i>>3)&3)
  const int srow  = lane >> 2;
  const int schk8 = ((lane & 3) ^ ((lane >> 3) & 3)) * 8;

  const ushort_t* gA[2];
  const ushort_t* gB[2];
  int aoff[2];
  const int bstride = (APATH == 1) ? 2048 : K;   // router B-fold: stride 2048
  const ushort_t* Bt = B + (EXPERT ? (size_t)(e - e0) * (size_t)N * K : 0);
  #pragma unroll
  for (int h = 0; h < 2; h++) {
    int r  = row0 + h * 64 + wid * 16 + srow;
    int rl = min(r, m_cnt - 1);              // clamp; OOB rows discarded in epilogue
    size_t rowb;
    if (APATH == 2)      rowb = (size_t)slot_token[m_base + rl] * 2048;
    else if (APATH == 1) rowb = (size_t)rl * 2048;
    else                 rowb = (size_t)(m_base + rl) * (size_t)K;
    gA[h]   = A + rowb + (APATH == 0 ? kbeg : 0) + schk8;
    aoff[h] = (h * 64 + wid * 16) * 32;

    int n = col0 + h * 64 + wid * 16 + srow;
    gB[h] = Bt + (size_t)n * bstride + kbeg + schk8;
  }

  // per wave: 4 DMAs per stage (2 A + 2 B) -> counted vmcnt(4)
  auto stage = [&](int pb, int kt) {
    const int k0 = kt << 5;
    // router folds (boundaries 32-aligned, k0 wave-uniform -> never straddle):
    // A: k' in [2048,3072) reads xh cols k'-2048.
    // B: k' >= 1024 reads stride-2048 rows at k'-1024 (wh copy / wl segment).
    const int k0a = (APATH == 1 && k0 >= 2048) ? k0 - 2048 : k0;
    const int k0b = (APATH == 1 && k0 >= 1024) ? k0 - 1024 : k0;
    #pragma unroll
    for (int h = 0; h < 2; h++) {
      gl2lds16(gA[h] + k0a, &As[pb][aoff[h]]);
      gl2lds16(gB[h] + k0b, &Bs[pb][aoff[h]]);
    }
  };

  f32x4 acc[4][4];
  #pragma unroll
  for (int i = 0; i < 4; i++)
    #pragma unroll
    for (int j = 0; j < 4; j++)
      acc[i][j] = (f32x4){0.f, 0.f, 0.f, 0.f};

  // fragment read constants
  const int q  = lane >> 4;
  const int rr = lane & 15;
  const int sw8 = (q ^ ((rr >> 1) & 3)) * 8;
  const int abase = (wm * 64 + rr) * 32 + sw8;
  const int bbase = (wn * 64 + rr) * 32 + sw8;

  const int nkt = Kc >> 5;

  stage(0, 0);
  if (nkt > 1) stage(1, 1);

  for (int kt = 0; kt < nkt; kt++) {
    // tile kt complete when <=4 outstanding (only stage(kt+1) newer).
    if (kt + 1 < nkt) asm volatile("s_waitcnt vmcnt(4)" ::: "memory");
    else              asm volatile("s_waitcnt vmcnt(0)" ::: "memory");
    __builtin_amdgcn_s_barrier();          // all waves' tile-kt DMAs landed
    __builtin_amdgcn_sched_barrier(0);
    // buf[(kt+2)%3] was read at kt-1; every wave passed its kt-1 lgkmcnt(0)
    // before this barrier -> safe to overwrite now.
    if (kt + 2 < nkt) stage((kt + 2) % 3, kt + 2);

    const int cur = kt % 3;
    short8 af[4], bfr[4];
    #pragma unroll
    for (int i = 0; i < 4; i++) {
      af[i]  = *(const short8*)(&As[cur][abase + i * 512]);
      bfr[i] = *(const short8*)(&Bs[cur][bbase + i * 512]);
    }
    asm volatile("s_waitcnt lgkmcnt(0)" ::: "memory");
    __builtin_amdgcn_sched_barrier(0);     // rule 18: keep MFMAs below the wait
    #pragma unroll
    for (int mt = 0; mt < 4; mt++)
      #pragma unroll
      for (int nt = 0; nt < 4; nt++)
        acc[mt][nt] = __builtin_amdgcn_mfma_f32_16x16x32_bf16(af[mt], bfr[nt], acc[mt][nt], 0, 0, 0);
  }

  // epilogue. C/D layout: col=lane&15, row=(lane>>4)*4+i  (m89-verified)
  const float* biasp = bias + (EXPERT ? (size_t)e * N : 0);
  float bv[4];
  #pragma unroll
  for (int nt = 0; nt < 4; nt++)
    bv[nt] = biasp[col0 + wn * 64 + nt * 16 + rr];
  const float bscale = (SPLITK == 1 || kc == 0) ? 1.f : 0.f;

  if constexpr (OUTMODE == 4) {
    // fused router score: partial[row][xi2][e] = sum_{c in 64-col chunk}
    // relu(h[row][c]) * rw2[c][e].  xi2 = (col0>>6)+wn; waves wn=0/1 cover
    // disjoint 64-col halves -> disjoint xi2.  All 16 lanes of a q-group
    // butterfly-reduce over rr; lane rr==0 stores 8 floats.
    const float* rw2p = slot_gate;           // repurposed: rw2 [DFF][8]
    float4 wa[4], wb[4];
    #pragma unroll
    for (int nt = 0; nt < 4; nt++) {
      int c = col0 + wn * 64 + nt * 16 + rr;
      wa[nt] = *(const float4*)(rw2p + (size_t)c * 8);
      wb[nt] = *(const float4*)(rw2p + (size_t)c * 8 + 4);
    }
    float* Ps = (float*)Cout;
    const int xi2 = (col0 >> 6) + wn;
    #pragma unroll
    for (int mt = 0; mt < 4; mt++) {
      #pragma unroll
      for (int i = 0; i < 4; i++) {
        float4 sA = {0.f, 0.f, 0.f, 0.f}, sB = {0.f, 0.f, 0.f, 0.f};
        #pragma unroll
        for (int nt = 0; nt < 4; nt++) {
          float v = acc[mt][nt][i] + bv[nt];
          if (RELU) v = fmaxf(v, 0.f);
          sA.x += v * wa[nt].x; sA.y += v * wa[nt].y;
          sA.z += v * wa[nt].z; sA.w += v * wa[nt].w;
          sB.x += v * wb[nt].x; sB.y += v * wb[nt].y;
          sB.z += v * wb[nt].z; sB.w += v * wb[nt].w;
        }
        #pragma unroll
        for (int o = 1; o <= 8; o <<= 1) {   // reduce over rr (16-lane group)
          sA.x += __shfl_xor(sA.x, o); sA.y += __shfl_xor(sA.y, o);
          sA.z += __shfl_xor(sA.z, o); sA.w += __shfl_xor(sA.w, o);
          sB.x += __shfl_xor(sB.x, o); sB.y += __shfl_xor(sB.y, o);
          sB.z += __shfl_xor(sB.z, o); sB.w += __shfl_xor(sB.w, o);
        }
        if (rr == 0) {
          int row = row0 + wm * 64 + mt * 16 + q * 4 + i;
          float* p = Ps + ((size_t)row * 64 + xi2) * 8;
          *(float4*)p       = sA;
          *(float4*)(p + 4) = sB;
        }
      }
    }
  } else {
    #pragma unroll
    for (int mt = 0; mt < 4; mt++) {
      #pragma unroll
      for (int i = 0; i < 4; i++) {
        int r_loc = row0 + wm * 64 + mt * 16 + q * 4 + i;
        if (r_loc < m_cnt) {
          int slot = m_base + r_loc;
          float g = 1.f;
          if (OUTMODE == 3) g = slot_gate[slot];
          #pragma unroll
          for (int nt = 0; nt < 4; nt++) {
            float v = acc[mt][nt][i] + bscale * bv[nt];
            if (RELU) v = fmaxf(v, 0.f);
            int c = col0 + wn * 64 + nt * 16 + rr;
            if (OUTMODE == 0)      ((float*)Cout)[(size_t)slot * N + c]    = v;
            else if (OUTMODE == 1) ((ushort_t*)Cout)[(size_t)slot * N + c] = f2bf(v);
            else ((float*)Cout)[((size_t)kc * SLOTS + slot) * N + c] = g * v;
          }
        }
      }
    }
  }
}

// score[t][e] = sum_xi2 Ps[t][xi2][e] + rb2[e]; top-2 + softmax gates + counts.
// One wave per token; lane l holds chunk xi2=l (coalesced 2KB row read).
__global__ void router_reduce(const float* __restrict__ Ps, const float* __restrict__ rb2,
                              int* __restrict__ topi, float* __restrict__ gates,
                              int* __restrict__ counts)
{
  int t = blockIdx.x * 4 + (threadIdx.x >> 6);
  if (t >= TOKENS) return;
  int lane = threadIdx.x & 63;
  const float* pt = Ps + (size_t)t * 512;
  float4 v0 = *(const float4*)(pt + lane * 8);
  float4 v1 = *(const float4*)(pt + lane * 8 + 4);
  #pragma unroll
  for (int o = 1; o <= 32; o <<= 1) {       // reduce over the 64 chunks
    v0.x += __shfl_xor(v0.x, o); v0.y += __shfl_xor(v0.y, o);
    v0.z += __shfl_xor(v0.z, o); v0.w += __shfl_xor(v0.w, o);
    v1.x += __shfl_xor(v1.x, o); v1.y += __shfl_xor(v1.y, o);
    v1.z += __shfl_xor(v1.z, o); v1.w += __shfl_xor(v1.w, o);
  }
  if (lane == 0) {
    float s[8] = {v0.x + rb2[0], v0.y + rb2[1], v0.z + rb2[2], v0.w + rb2[3],
                  v1.x + rb2[4], v1.y + rb2[5], v1.z + rb2[6], v1.w + rb2[7]};
    int i0 = 0;
    #pragma unroll
    for (int e = 1; e < 8; e++) if (s[e] > s[i0]) i0 = e;   // ties -> lower idx (jax)
    int i1 = (i0 == 0) ? 1 : 0;
    #pragma unroll
    for (int e = 0; e < 8; e++) if (e != i0 && s[e] > s[i1]) i1 = e;
    float ex = __expf(s[i1] - s[i0]);
    float g0 = 1.f / (1.f + ex);
    float g1 = ex / (1.f + ex);
    topi[t * 2] = i0; topi[t * 2 + 1] = i1;
    gates[t * 2] = g0; gates[t * 2 + 1] = g1;
    atomicAdd(&counts[i0], 1);
    atomicAdd(&counts[i1], 1);
  }
}

// prefix_off + assign_slots fused: one block, LDS cursors.
__global__ void assign_all(const int* __restrict__ counts, const int* __restrict__ topi,
                           const float* __restrict__ gates, int* __restrict__ off,
                           int* __restrict__ tile_e, int* __restrict__ tile_y,
                           int* __restrict__ slot_token, float* __restrict__ slot_gate,
                           int* __restrict__ tok_slot)
{
  __shared__ int s_off[NEXP];
  __shared__ int s_cur[NEXP];
  int tid = threadIdx.x;
  if (tid < NEXP) s_cur[tid] = 0;
  if (tid == 0) {
    int a = 0, t = 0;
    for (int e = 0; e < NEXP; e++) {
      off[e] = a; s_off[e] = a;
      int c = counts[e]; a += c;
      int ty = (c + 127) >> 7;
      for (int y = 0; y < ty; y++) { tile_e[t] = e; tile_y[t] = y; t++; }
    }
    off[NEXP] = a;
    for (; t < TMAX; t++) { tile_e[t] = -1; tile_y[t] = 0; }
  }
  __syncthreads();
  for (int t = tid; t < TOKENS; t += 256) {
    #pragma unroll
    for (int k = 0; k < 2; k++) {
      int e = topi[t * 2 + k];
      int p = atomicAdd(&s_cur[e], 1);
      int s = s_off[e] + p;
      slot_token[s] = t;
      slot_gate[s]  = gates[t * 2 + k];
      tok_slot[t * 2 + k] = s;
    }
  }
}

// out[t] = sum over {2 slots} x {NC k-chunks} of gated partials (gate/bias folded)
template<int NC>
__global__ void combine_out(const float* __restrict__ Ys, const int* __restrict__ tok_slot,
                            float* __restrict__ out)
{
  int t = blockIdx.x;
  int d = threadIdx.x * 4;
  int s0 = tok_slot[t * 2], s1 = tok_slot[t * 2 + 1];
  float4 o = {0.f, 0.f, 0.f, 0.f};
  #pragma unroll
  for (int k = 0; k < NC; k++) {
    float4 a = *(const float4*)(Ys + ((size_t)k * SLOTS + s0) * EMBED + d);
    float4 b = *(const float4*)(Ys + ((size_t)k * SLOTS + s1) * EMBED + d);
    o.x += a.x + b.x;
    o.y += a.y + b.y;
    o.z += a.z + b.z;
    o.w += a.w + b.w;
  }
  *(float4*)(out + (size_t)t * EMBED + d) = o;
}

extern "C" void kernel_launch(void* const* d_in, const int* in_sizes, int n_in,
                              void* d_out, int out_size, void* d_ws, size_t ws_size,
                              hipStream_t stream)
{
  const float* x   = (const float*)d_in[0];
  const float* rw1 = (const float*)d_in[1];
  const float* rb1 = (const float*)d_in[2];
  const float* rw2 = (const float*)d_in[3];
  const float* rb2 = (const float*)d_in[4];
  const float* W1  = (const float*)d_in[5];
  const float* b1  = (const float*)d_in[6];
  const float* W2  = (const float*)d_in[7];
  const float* b2  = (const float*)d_in[8];
  float* out = (float*)d_out;
  char* ws = (char*)d_ws;

  const long W1ES = (long)EMBED * DFF;   // floats per expert
  const long W2ES = (long)DFF * EMBED;
  const size_t SZ_R = (size_t)4096 * 4096 * 2;   // 33.5 MB

  const bool FULL = ws_size >= ((size_t)300 << 20);

  if (FULL) {
    // Full layout (~232 MB; ws = 512 MiB per R8 fill evidence):
    // [W1T 67][W2T 67][RW1t 16.8][Hs 33.5][Xhl 8.4][Ys(2) 33.5][Ps 4][small]
    char* p = ws;
    ushort_t* W1T  = (ushort_t*)p;  p += (size_t)NEXP * DFF * EMBED * 2;
    ushort_t* W2T  = (ushort_t*)p;  p += (size_t)NEXP * EMBED * DFF * 2;
    ushort_t* RW1t = (ushort_t*)p;  p += (size_t)4096 * 2048 * 2;
    ushort_t* Hs   = (ushort_t*)p;  p += (size_t)SLOTS * DFF * 2;
    ushort_t* Xhl  = (ushort_t*)p;  p += (size_t)TOKENS * 2048 * 2;
    float*    Ys   = (float*)p;     p += (size_t)2 * SLOTS * EMBED * 4;
    float*    Ps   = (float*)p;     p += (size_t)TOKENS * 512 * 4;
    int*   topi       = (int*)p;    p += TOKENS * 2 * 4;
    float* gates      = (float*)p;  p += TOKENS * 2 * 4;
    int*   tok_slot   = (int*)p;    p += TOKENS * 2 * 4;
    int*   slot_token = (int*)p;    p += SLOTS * 4;
    float* slot_gate  = (float*)p;  p += SLOTS * 4;
    int*   counts     = (int*)p;    p += 256;
    int*   off        = (int*)p;    p += 256;
    int*   tile_e     = (int*)p;    p += 256;
    int*   tile_y     = (int*)p;    p += 256;

    // (1) prep: zero + split + single-pass rw1 transpose (1024 blocks)
    prep_kernel<<<TOKENS + 1024, 256, 0, stream>>>(x, Xhl, rw1, RW1t, counts);

    // (2) Router GEMM (512 blocks @3/CU -> 256 leftover slots) + W1T transp.
    gemm_kernel<1, 4, true, false, 1, 32, 1>
        <<<dim3(512 + 8192, 1, 1), 256, 0, stream>>>(Xhl, RW1t, rb1, Ps, rw2,
            nullptr, nullptr, nullptr, nullptr, 0, NEXP, TOKENS, DFF, 3072,
            512, W1, W1T);

    router_reduce<<<512, 256, 0, stream>>>(Ps, rb2, topi, gates, counts);
    assign_all<<<1, 256, 0, stream>>>(counts, topi, gates, off, tile_e, tile_y,
                                      slot_token, slot_gate, tok_slot);

    // (3) GEMM1 (reads W1T from launch 2) + W2T transp (8192 blocks).
    gemm_kernel<2, 1, true, true, 1, 32, 2>
        <<<dim3(8 * TG * 32 + 8192, 1, 1), 256, 0, stream>>>(Xhl, W1T, b1, Hs,
            nullptr, slot_token, off, tile_e, tile_y, 0, NEXP, 0, DFF, EMBED,
            8 * TG * 32, W2, W2T);

    // (4) GEMM2 SPLITK=2 (640 blocks fit 768 slots)
    gemm_kernel<0, 3, false, true, 2, 8, 0>
        <<<dim3(8 * TG * 16, 1, 1), 256, 0, stream>>>(Hs, W2T, b2, Ys,
            slot_gate, nullptr, off, tile_e, tile_y, 0, NEXP, 0, EMBED, DFF,
            0, nullptr, nullptr);

    combine_out<2><<<TOKENS, 256, 0, stream>>>(Ys, tok_slot, out);
  } else {
    // Fallback: half-by-half weight staging (~109 MB proven)
    ushort_t* RW1t = (ushort_t*)ws;                 // region A
    ushort_t* WT   = (ushort_t*)ws;
    ushort_t* Hs   = (ushort_t*)(ws + SZ_R);        // region B
    ushort_t* Xhl  = (ushort_t*)(ws + 2 * SZ_R);    // region C
    float*    Ys   = (float*)(ws + 2 * SZ_R);
    char* p = ws + 3 * SZ_R;
    float* Ps         = (float*)p;  p += (size_t)TOKENS * 512 * 4;  // 4MB
    int*   topi       = (int*)p;    p += TOKENS * 2 * 4;
    float* gates      = (float*)p;  p += TOKENS * 2 * 4;
    int*   tok_slot   = (int*)p;    p += TOKENS * 2 * 4;
    int*   slot_token = (int*)p;    p += SLOTS * 4;
    float* slot_gate  = (float*)p;  p += SLOTS * 4;
    int*   counts     = (int*)p;    p += 256;
    int*   off        = (int*)p;    p += 256;
    int*   tile_e     = (int*)p;    p += 256;
    int*   tile_y     = (int*)p;    p += 256;

    prep_kernel<<<TOKENS + 1024, 256, 0, stream>>>(x, Xhl, rw1, RW1t, counts);

    gemm_kernel<1, 4, true, false, 1, 32, 0>
        <<<dim3(512, 1, 1), 256, 0, stream>>>(Xhl, RW1t, rb1, Ps, rw2, nullptr,
            nullptr, nullptr, nullptr, 0, NEXP, TOKENS, DFF, 3072,
            0, nullptr, nullptr);
    router_reduce<<<512, 256, 0, stream>>>(Ps, rb2, topi, gates, counts);
    assign_all<<<1, 256, 0, stream>>>(counts, topi, gates, off, tile_e, tile_y,
                                      slot_token, slot_gate, tok_slot);

    for (int half = 0; half < 2; half++) {
      int e0 = half * 4;
      transp_conv<<<dim3(64, 16, 4), 256, 0, stream>>>(W1 + (size_t)e0 * W1ES, WT,
          DFF, EMBED, W1ES, W1ES, 0, 0);
      gemm_kernel<2, 1, true, true, 1, 32, 0>
          <<<dim3(8 * TG * 32, 1, 1), 256, 0, stream>>>(Xhl, WT, b1, Hs,
              nullptr, slot_token, off, tile_e, tile_y, e0, e0 + 4, 0, DFF, EMBED,
              0, nullptr, nullptr);
    }
    for (int half = 0; half < 2; half++) {
      int e0 = half * 4;
      transp_conv<<<dim3(16, 64, 4), 256, 0, stream>>>(W2 + (size_t)e0 * W2ES, WT,
          EMBED, DFF, W2ES, W2ES, 0, 0);
      gemm_kernel<0, 3, false, true, 2, 8, 0>
          <<<dim3(8 * TG * 16, 1, 1), 256, 0, stream>>>(Hs, WT, b2, Ys,
              slot_gate, nullptr, off, tile_e, tile_y, e0, e0 + 4, 0, EMBED, DFF,
              0, nullptr, nullptr);
    }

    combine_out<2><<<TOKENS, 256, 0, stream>>>(Ys, tok_slot, out);
  }
}